// Round 3
// baseline (197.561 us; speedup 1.0000x reference)
//
#include <hip/hip_runtime.h>
#include <hip/hip_bf16.h>
#include <math.h>

#define BB 32
#define TT 4096
#define NN 11
#define FF 16
#define HH 32
#define LN_EPS 1e-5f

// Block: 256 threads = 64 tokens x 4 f-chunks. 2048 blocks total.
// Wave wv owns tokens [16wv,16wv+16) -> LDS rows [176wv,176wv+176) -> 11 MFMA tiles.
#define TOKENS_PER_BLOCK 64
#define NBLOCKS (BB * TT / TOKENS_PER_BLOCK)          // 2048
#define BLOCKS_PER_BATCH (TT / TOKENS_PER_BLOCK)      // 64 (exact) -> lab uniform
#define ROW_STRIDE_B 32                               // exactly 16 bf16; 22528 B LDS -> 7 blocks/CU

typedef __attribute__((ext_vector_type(8))) short short8;  // 8 bf16 = 4 VGPRs
typedef __attribute__((ext_vector_type(4))) float f32x4;

union Frag { unsigned u[4]; uint4 u4; short8 v; };

__device__ __forceinline__ unsigned pack2_bf16(float a, float b) {
    __hip_bfloat162 p = __float22bfloat162_rn(make_float2(a, b));
    union { __hip_bfloat162 h; unsigned u; } cvt; cvt.h = p; return cvt.u;
}

// tanh-form GELU via sigmoid; max dev from exact-erf GELU ~3e-3
__device__ __forceinline__ float fast_gelu(float v) {
    const float v2 = v * v;
    const float c  = fmaf(0.044715f, v2, 1.0f);
    const float t  = v * c * 1.5957691216057308f;
    const float e  = __expf(-t);
    return v * __builtin_amdgcn_rcpf(1.0f + e);
}

__global__ __launch_bounds__(256) void fused_v8(
    const float* __restrict__ x,        // [B,T,N,F]
    const int*   __restrict__ lab_idx,  // [B]
    const float* __restrict__ proj,     // [L,N,N]
    const float* __restrict__ bias,     // [L,1,N,F]
    const float* __restrict__ w1,       // [F,H]
    const float* __restrict__ b1,       // [H]
    const float* __restrict__ ln_g,     // [H]
    const float* __restrict__ ln_b,     // [H]
    const float* __restrict__ w2,       // [H,F]
    const float* __restrict__ b2,       // [F]
    float*       __restrict__ out)      // [B,T,N,F]
{
    // 704 rows x 32 B = 22528 B. Row r = tl*11 + m (token-major, matches out order).
    __shared__ __align__(16) unsigned char o_st[704 * ROW_STRIDE_B];

    const int tid  = threadIdx.x;
    const int wv   = tid >> 6;
    const int lane = tid & 63;
    const int q    = lane >> 4;
    const int c    = lane & 15;
    const int tl   = tid >> 2;          // token-local 0..63
    const int f4   = tid & 3;           // f-chunk 0..3

    const int token = blockIdx.x * TOKENS_PER_BLOCK + tl;
    const int lab   = lab_idx[blockIdx.x / BLOCKS_PER_BATCH];   // block-uniform -> SGPR

    // ---------- projection: m-outer (ROLLED), 4-reg accumulator, fused LDS staging ----
    // Inner n-loop stays unrolled so xv[n] is compile-time-indexed (stays in VGPRs).
    // Loops rolled to shrink code from ~25KB (fully unrolled) to ~3KB: R2 counters
    // showed VALUBusy pinned at 42% across occupancy changes -> I-fetch-bound theory.
    const float4* xb = reinterpret_cast<const float4*>(x)    + (size_t)token * (NN * FF / 4) + f4;
    const float4* bb = reinterpret_cast<const float4*>(bias) + (size_t)lab   * (NN * FF / 4) + f4;
    const float*  Wl = proj + (size_t)lab * (NN * NN);       // uniform base -> s_load

    float4 xv[NN];
    #pragma unroll
    for (int n = 0; n < NN; ++n) xv[n] = xb[4 * n];

    unsigned char* orow = &o_st[(tl * NN) * ROW_STRIDE_B + f4 * 8];
    #pragma unroll 1
    for (int m = 0; m < NN; ++m) {
        const float4 bv = bb[4 * m];
        float o0 = bv.x, o1 = bv.y, o2 = bv.z, o3 = bv.w;
        #pragma unroll
        for (int n = 0; n < NN; ++n) {
            const float wm = Wl[n * NN + m];   // uniform -> SGPR operand
            o0 = fmaf(xv[n].x, wm, o0);
            o1 = fmaf(xv[n].y, wm, o1);
            o2 = fmaf(xv[n].z, wm, o2);
            o3 = fmaf(xv[n].w, wm, o3);
        }
        uint2 p;
        p.x = pack2_bf16(o0, o1);
        p.y = pack2_bf16(o2, o3);
        *reinterpret_cast<uint2*>(orow + m * ROW_STRIDE_B) = p;
    }
    // no __syncthreads: rows [176wv,176wv+176) were written by this wave's own lanes;
    // same-wave LDS ops are pipe-ordered.

    // ---------- weight fragments as A-operands (verified in R4) ----------
    Frag a1c0, a1c1, a2f;
    #pragma unroll
    for (int d = 0; d < 4; ++d) {
        const int k0 = 8 * q + 2 * d;
        float wa0 = 0.f, wa1 = 0.f, wb0 = 0.f, wb1 = 0.f;
        if (q < 2) {
            wa0 = w1[k0 * HH + c];       wa1 = w1[(k0 + 1) * HH + c];
            wb0 = w1[k0 * HH + 16 + c];  wb1 = w1[(k0 + 1) * HH + 16 + c];
        }
        a1c0.u[d] = pack2_bf16(wa0, wa1);
        a1c1.u[d] = pack2_bf16(wb0, wb1);
        a2f.u[d]  = pack2_bf16(w2[k0 * FF + c], w2[(k0 + 1) * FF + c]);
    }

    float4 b1v0 = *reinterpret_cast<const float4*>(b1 + 4 * q);
    float4 b1v1 = *reinterpret_cast<const float4*>(b1 + 16 + 4 * q);
    float4 b2v  = *reinterpret_cast<const float4*>(b2 + 4 * q);
    float4 g0   = *reinterpret_cast<const float4*>(ln_g + 4 * q);
    float4 g1   = *reinterpret_cast<const float4*>(ln_g + 16 + 4 * q);
    float4 e0   = *reinterpret_cast<const float4*>(ln_b + 4 * q);
    float4 e1   = *reinterpret_cast<const float4*>(ln_b + 16 + 4 * q);
    float g0a[4] = {g0.x, g0.y, g0.z, g0.w}, g1a[4] = {g1.x, g1.y, g1.z, g1.w};
    float e0a[4] = {e0.x, e0.y, e0.z, e0.w}, e1a[4] = {e1.x, e1.y, e1.z, e1.w};
    float b1a0[4] = {b1v0.x, b1v0.y, b1v0.z, b1v0.w};
    float b1a1[4] = {b1v1.x, b1v1.y, b1v1.z, b1v1.w};
    float b2a[4]  = {b2v.x, b2v.y, b2v.z, b2v.w};

    const size_t outrow0 = (size_t)blockIdx.x * (TOKENS_PER_BLOCK * NN) + wv * 176;
    const int srcA = (q & 1) * 32 + c;
    const int srcB = srcA + 16;

    #pragma unroll 1
    for (int t = 0; t < NN; ++t) {
        // ---- GEMM1 (transposed): B1[k=f][col=c] = o_bf16[row 176wv+16t+c][f]
        Frag B1;
        B1.u4 = *reinterpret_cast<const uint4*>(
            &o_st[(176 * wv + 16 * t + c) * ROW_STRIDE_B + (q & 1) * 16]);

        f32x4 accA = { b1a0[0], b1a0[1], b1a0[2], b1a0[3] };
        f32x4 accB = { b1a1[0], b1a1[1], b1a1[2], b1a1[3] };
        accA = __builtin_amdgcn_mfma_f32_16x16x32_bf16(a1c0.v, B1.v, accA, 0, 0, 0);
        accB = __builtin_amdgcn_mfma_f32_16x16x32_bf16(a1c1.v, B1.v, accB, 0, 0, 0);

        // ---- LayerNorm over H=32 (column c's values live in lanes c, c+16, c+32, c+48)
        float s = 0.f, ss = 0.f;
        #pragma unroll
        for (int i = 0; i < 4; ++i) {
            s += accA[i] + accB[i];
            ss = fmaf(accA[i], accA[i], ss);
            ss = fmaf(accB[i], accB[i], ss);
        }
        s  += __shfl_xor(s, 16, 64);  s  += __shfl_xor(s, 32, 64);
        ss += __shfl_xor(ss, 16, 64); ss += __shfl_xor(ss, 32, 64);
        const float mu   = s * (1.f / HH);
        const float var  = ss * (1.f / HH) - mu * mu;
        const float rstd = rsqrtf(var + LN_EPS);
        const float nb   = -mu * rstd;

        // ---- affine + GELU
        float ga[4], gb[4];
        #pragma unroll
        for (int i = 0; i < 4; ++i) {
            ga[i] = fast_gelu(fmaf(fmaf(accA[i], rstd, nb), g0a[i], e0a[i]));
            gb[i] = fast_gelu(fmaf(fmaf(accB[i], rstd, nb), g1a[i], e1a[i]));
        }
        const unsigned c0d0 = pack2_bf16(ga[0], ga[1]);
        const unsigned c0d1 = pack2_bf16(ga[2], ga[3]);
        const unsigned c1d0 = pack2_bf16(gb[0], gb[1]);
        const unsigned c1d1 = pack2_bf16(gb[2], gb[3]);

        // ---- register transpose to B2-frag (verified in R4)
        Frag B2;
        {
            unsigned lo, hi;
            lo = __shfl((int)c0d0, srcA, 64); hi = __shfl((int)c1d0, srcA, 64);
            B2.u[0] = (q < 2) ? lo : hi;
            lo = __shfl((int)c0d1, srcA, 64); hi = __shfl((int)c1d1, srcA, 64);
            B2.u[1] = (q < 2) ? lo : hi;
            lo = __shfl((int)c0d0, srcB, 64); hi = __shfl((int)c1d0, srcB, 64);
            B2.u[2] = (q < 2) ? lo : hi;
            lo = __shfl((int)c0d1, srcB, 64); hi = __shfl((int)c1d1, srcB, 64);
            B2.u[3] = (q < 2) ? lo : hi;
        }

        // ---- GEMM2 (transposed, K=32): out^T[f=4q+i][col=c]
        f32x4 acc2 = { b2a[0], b2a[1], b2a[2], b2a[3] };
        acc2 = __builtin_amdgcn_mfma_f32_16x16x32_bf16(a2f.v, B2.v, acc2, 0, 0, 0);

        // ---- contiguous float4 store: row = outrow0 + 16t + c, f = 4q..4q+3
        float4* dst = reinterpret_cast<float4*>(out + (outrow0 + 16 * t + c) * FF + 4 * q);
        *dst = make_float4(acc2[0], acc2[1], acc2[2], acc2[3]);
    }
}

extern "C" void kernel_launch(void* const* d_in, const int* in_sizes, int n_in,
                              void* d_out, int out_size, void* d_ws, size_t ws_size,
                              hipStream_t stream) {
    const float* x       = (const float*)d_in[0];
    const int*   lab_idx = (const int*)  d_in[1];
    const float* proj    = (const float*)d_in[2];
    const float* bias    = (const float*)d_in[3];
    const float* w1      = (const float*)d_in[4];
    const float* b1      = (const float*)d_in[5];
    const float* ln_g    = (const float*)d_in[6];
    const float* ln_b    = (const float*)d_in[7];
    const float* w2      = (const float*)d_in[8];
    const float* b2      = (const float*)d_in[9];
    float* out = (float*)d_out;

    fused_v8<<<NBLOCKS, 256, 0, stream>>>(
        x, lab_idx, proj, bias, w1, b1, ln_g, ln_b, w2, b2, out);
}

// Round 4
// 189.573 us; speedup vs baseline: 1.0421x; 1.0421x over previous
//
#include <hip/hip_runtime.h>
#include <hip/hip_bf16.h>
#include <math.h>

#define BB 32
#define TT 4096
#define NN 11
#define FF 16
#define HH 32
#define LN_EPS 1e-5f

// Block: 256 threads = 64 tokens x 4 f-chunks. 2048 blocks total.
// Wave wv owns tokens [16wv,16wv+16) -> LDS rows [176wv,176wv+176) -> 11 MFMA tiles.
#define TOKENS_PER_BLOCK 64
#define NBLOCKS (BB * TT / TOKENS_PER_BLOCK)          // 2048
#define BLOCKS_PER_BATCH (TT / TOKENS_PER_BLOCK)      // 64 (exact) -> lab uniform
#define ROW_STRIDE_B 32                               // exactly 16 bf16; 22528 B LDS -> 7 blocks/CU

typedef __attribute__((ext_vector_type(8))) short short8;  // 8 bf16 = 4 VGPRs
typedef __attribute__((ext_vector_type(4))) float f32x4;

union Frag { unsigned u[4]; uint4 u4; short8 v; };

__device__ __forceinline__ unsigned pack2_bf16(float a, float b) {
    __hip_bfloat162 p = __float22bfloat162_rn(make_float2(a, b));
    union { __hip_bfloat162 h; unsigned u; } cvt; cvt.h = p; return cvt.u;
}

// tanh-form GELU via sigmoid; max dev from exact-erf GELU ~3e-3
__device__ __forceinline__ float fast_gelu(float v) {
    const float v2 = v * v;
    const float c  = fmaf(0.044715f, v2, 1.0f);
    const float t  = v * c * 1.5957691216057308f;
    const float e  = __expf(-t);
    return v * __builtin_amdgcn_rcpf(1.0f + e);
}

// v9: transpose-free GEMM1->GEMM2 handoff.
// A1 tile row r holds w1-column hA(r)=8*(r/4)+(r%4) (a1c0) / hA(r)+4 (a1c1).
// => lane (q,c) accumulates h-dims {8q..8q+3} (accA), {8q+4..8q+7} (accB),
//    which IS the B-fragment k-layout for GEMM2: B2 = 4 local packs, no shuffles.
__global__ __launch_bounds__(256) void fused_v9(
    const float* __restrict__ x,        // [B,T,N,F]
    const int*   __restrict__ lab_idx,  // [B]
    const float* __restrict__ proj,     // [L,N,N]
    const float* __restrict__ bias,     // [L,1,N,F]
    const float* __restrict__ w1,       // [F,H]
    const float* __restrict__ b1,       // [H]
    const float* __restrict__ ln_g,     // [H]
    const float* __restrict__ ln_b,     // [H]
    const float* __restrict__ w2,       // [H,F]
    const float* __restrict__ b2,       // [F]
    float*       __restrict__ out)      // [B,T,N,F]
{
    // 704 rows x 32 B = 22528 B. Row r = tl*11 + m (token-major, matches out order).
    __shared__ __align__(16) unsigned char o_st[704 * ROW_STRIDE_B];

    const int tid  = threadIdx.x;
    const int wv   = tid >> 6;
    const int lane = tid & 63;
    const int q    = lane >> 4;
    const int c    = lane & 15;
    const int tl   = tid >> 2;          // token-local 0..63
    const int f4   = tid & 3;           // f-chunk 0..3

    const int token = blockIdx.x * TOKENS_PER_BLOCK + tl;
    const int lab   = lab_idx[blockIdx.x / BLOCKS_PER_BATCH];   // block-uniform -> SGPR

    // ---------- projection: m-outer, 4-reg accumulator, fused LDS staging ----------
    const float4* xb = reinterpret_cast<const float4*>(x)    + (size_t)token * (NN * FF / 4) + f4;
    const float4* bb = reinterpret_cast<const float4*>(bias) + (size_t)lab   * (NN * FF / 4) + f4;
    const float*  Wl = proj + (size_t)lab * (NN * NN);       // uniform base -> s_load

    float4 xv[NN];
    #pragma unroll
    for (int n = 0; n < NN; ++n) xv[n] = xb[4 * n];

    unsigned char* orow = &o_st[(tl * NN) * ROW_STRIDE_B + f4 * 8];
    #pragma unroll
    for (int m = 0; m < NN; ++m) {
        const float4 bv = bb[4 * m];
        float o0 = bv.x, o1 = bv.y, o2 = bv.z, o3 = bv.w;
        #pragma unroll
        for (int n = 0; n < NN; ++n) {
            const float wm = Wl[n * NN + m];   // uniform -> SGPR operand
            o0 = fmaf(xv[n].x, wm, o0);
            o1 = fmaf(xv[n].y, wm, o1);
            o2 = fmaf(xv[n].z, wm, o2);
            o3 = fmaf(xv[n].w, wm, o3);
        }
        uint2 p;
        p.x = pack2_bf16(o0, o1);
        p.y = pack2_bf16(o2, o3);
        *reinterpret_cast<uint2*>(orow + m * ROW_STRIDE_B) = p;
    }
    // no __syncthreads: rows [176wv,176wv+176) were written by this wave's own lanes;
    // same-wave LDS ops are pipe-ordered.

    // ---------- weight fragments as A-operands, PERMUTED columns (v9) ----------
    const int hA = 8 * (c >> 2) + (c & 3);   // h-dim assigned to tile row c (accA); accB = hA+4
    Frag a1c0, a1c1, a2f;
    #pragma unroll
    for (int d = 0; d < 4; ++d) {
        const int k0 = 8 * q + 2 * d;
        float wa0 = 0.f, wa1 = 0.f, wb0 = 0.f, wb1 = 0.f;
        if (q < 2) {
            wa0 = w1[k0 * HH + hA];       wa1 = w1[(k0 + 1) * HH + hA];
            wb0 = w1[k0 * HH + hA + 4];   wb1 = w1[(k0 + 1) * HH + hA + 4];
        }
        a1c0.u[d] = pack2_bf16(wa0, wa1);
        a1c1.u[d] = pack2_bf16(wb0, wb1);
        a2f.u[d]  = pack2_bf16(w2[k0 * FF + c], w2[(k0 + 1) * FF + c]);
    }

    // per-h-dim constants, re-indexed to the permuted layout: lane q owns h 8q..8q+7
    float4 b1v0 = *reinterpret_cast<const float4*>(b1 + 8 * q);
    float4 b1v1 = *reinterpret_cast<const float4*>(b1 + 8 * q + 4);
    float4 g0   = *reinterpret_cast<const float4*>(ln_g + 8 * q);
    float4 g1   = *reinterpret_cast<const float4*>(ln_g + 8 * q + 4);
    float4 e0   = *reinterpret_cast<const float4*>(ln_b + 8 * q);
    float4 e1   = *reinterpret_cast<const float4*>(ln_b + 8 * q + 4);
    float4 b2v  = *reinterpret_cast<const float4*>(b2 + 4 * q);
    float g0a[4] = {g0.x, g0.y, g0.z, g0.w}, g1a[4] = {g1.x, g1.y, g1.z, g1.w};
    float e0a[4] = {e0.x, e0.y, e0.z, e0.w}, e1a[4] = {e1.x, e1.y, e1.z, e1.w};
    float b1a0[4] = {b1v0.x, b1v0.y, b1v0.z, b1v0.w};
    float b1a1[4] = {b1v1.x, b1v1.y, b1v1.z, b1v1.w};
    float b2a[4]  = {b2v.x, b2v.y, b2v.z, b2v.w};

    const size_t outrow0 = (size_t)blockIdx.x * (TOKENS_PER_BLOCK * NN) + wv * 176;

    #pragma unroll
    for (int t = 0; t < NN; ++t) {
        // ---- GEMM1 (transposed): B1[k=f][col=c] = o_bf16[row 176wv+16t+c][f]
        Frag B1;
        B1.u4 = *reinterpret_cast<const uint4*>(
            &o_st[(176 * wv + 16 * t + c) * ROW_STRIDE_B + (q & 1) * 16]);

        f32x4 accA = { b1a0[0], b1a0[1], b1a0[2], b1a0[3] };
        f32x4 accB = { b1a1[0], b1a1[1], b1a1[2], b1a1[3] };
        accA = __builtin_amdgcn_mfma_f32_16x16x32_bf16(a1c0.v, B1.v, accA, 0, 0, 0);
        accB = __builtin_amdgcn_mfma_f32_16x16x32_bf16(a1c1.v, B1.v, accB, 0, 0, 0);
        // accA[i] = h[token c][8q+i], accB[i] = h[token c][8q+4+i]

        // ---- LayerNorm over H=32 (token c's values live in lanes c, c+16, c+32, c+48)
        float s = 0.f, ss = 0.f;
        #pragma unroll
        for (int i = 0; i < 4; ++i) {
            s += accA[i] + accB[i];
            ss = fmaf(accA[i], accA[i], ss);
            ss = fmaf(accB[i], accB[i], ss);
        }
        s  += __shfl_xor(s, 16, 64);  s  += __shfl_xor(s, 32, 64);
        ss += __shfl_xor(ss, 16, 64); ss += __shfl_xor(ss, 32, 64);
        const float mu   = s * (1.f / HH);
        const float var  = ss * (1.f / HH) - mu * mu;
        const float rstd = rsqrtf(var + LN_EPS);
        const float nb   = -mu * rstd;

        // ---- affine + GELU
        float ga[4], gb[4];
        #pragma unroll
        for (int i = 0; i < 4; ++i) {
            ga[i] = fast_gelu(fmaf(fmaf(accA[i], rstd, nb), g0a[i], e0a[i]));
            gb[i] = fast_gelu(fmaf(fmaf(accB[i], rstd, nb), g1a[i], e1a[i]));
        }

        // ---- B2 fragment is now LANE-LOCAL (no shuffles): k=8q+2d+j <-> h-dim identity
        Frag B2;
        B2.u[0] = pack2_bf16(ga[0], ga[1]);
        B2.u[1] = pack2_bf16(ga[2], ga[3]);
        B2.u[2] = pack2_bf16(gb[0], gb[1]);
        B2.u[3] = pack2_bf16(gb[2], gb[3]);

        // ---- GEMM2 (transposed, K=32): out^T[f=4q+i][col=c]
        f32x4 acc2 = { b2a[0], b2a[1], b2a[2], b2a[3] };
        acc2 = __builtin_amdgcn_mfma_f32_16x16x32_bf16(a2f.v, B2.v, acc2, 0, 0, 0);

        // ---- contiguous float4 store: row = outrow0 + 16t + c, f = 4q..4q+3
        float4* dst = reinterpret_cast<float4*>(out + (outrow0 + 16 * t + c) * FF + 4 * q);
        *dst = make_float4(acc2[0], acc2[1], acc2[2], acc2[3]);
    }
}

extern "C" void kernel_launch(void* const* d_in, const int* in_sizes, int n_in,
                              void* d_out, int out_size, void* d_ws, size_t ws_size,
                              hipStream_t stream) {
    const float* x       = (const float*)d_in[0];
    const int*   lab_idx = (const int*)  d_in[1];
    const float* proj    = (const float*)d_in[2];
    const float* bias    = (const float*)d_in[3];
    const float* w1      = (const float*)d_in[4];
    const float* b1      = (const float*)d_in[5];
    const float* ln_g    = (const float*)d_in[6];
    const float* ln_b    = (const float*)d_in[7];
    const float* w2      = (const float*)d_in[8];
    const float* b2      = (const float*)d_in[9];
    float* out = (float*)d_out;

    fused_v9<<<NBLOCKS, 256, 0, stream>>>(
        x, lab_idx, proj, bias, w1, b1, ln_g, ln_b, w2, b2, out);
}